// Round 18
// baseline (16084.247 us; speedup 1.0000x reference)
//
#include <hip/hip_runtime.h>
#include <cmath>

#define Bsz 64
#define Tsz 256
#define Hsz 1024
#define NTHR 512
#define WROWU 512   // uints per packed bf16 weight row

// counted vmem wait + scheduler fence (rule #18)
#define WAITVM(N) do {                                            \
    asm volatile("s_waitcnt vmcnt(" #N ")" ::: "memory");         \
    __builtin_amdgcn_sched_barrier(0);                            \
} while (0)

// ---------------- device-global scratch -------------------------------------
__device__ float g_h[2][2][Bsz * Hsz];      // [layer][parity][b*H+k]
__device__ float g_pre[2][Bsz];             // [parity][b] gate partial accum
__device__ float g_an[Tsz * Bsz];           // [t][b]: x[b,min(t+1,T-1)] . v1
__device__ float g_v1[Hsz];
__device__ float g_v2[Hsz];
__device__ float g_c;
__device__ unsigned g_bar_cnt[4 * 32];      // padded per-group barrier state
__device__ unsigned g_bar_gen[4 * 32];
__device__ float g_gi0[(size_t)Tsz * Bsz * 3 * Hsz];  // 201 MB: x@Wih0^T + bih0
__device__ unsigned g_w0[(size_t)3 * Hsz * WROWU];    // 6.3 MB bf16 L0-Whh rows

// ---------------- per-access coherent ops (NO L2-invalidating fences) -------
__device__ __forceinline__ float ldc(const float* p) {
    return __hip_atomic_load((const float*)p, __ATOMIC_RELAXED,
                             __HIP_MEMORY_SCOPE_AGENT);
}
__device__ __forceinline__ void stc(float* p, float v) {
    __hip_atomic_store(p, v, __ATOMIC_RELAXED, __HIP_MEMORY_SCOPE_AGENT);
}

// coherent 16B load: ONE request; sc0 sc1 = always-fresh
__device__ __forceinline__ void ldc4_issue(const float* p, float4& v) {
    asm volatile("global_load_dwordx4 %0, %1, off sc0 sc1"
                 : "=v"(v) : "v"(p));
}

// bf16-pair (low = even k, high = odd k) -> float4 via shift/mask
__device__ __forceinline__ float4 bfx4(uint2 u) {
    float4 f;
    f.x = __uint_as_float(u.x << 16);
    f.y = __uint_as_float(u.x & 0xffff0000u);
    f.z = __uint_as_float(u.y << 16);
    f.w = __uint_as_float(u.y & 0xffff0000u);
    return f;
}

__device__ __forceinline__ unsigned rne_bf16_pair(float a, float b) {
    unsigned u0 = __float_as_uint(a);
    unsigned u1 = __float_as_uint(b);
    u0 = (u0 + 0x7fffu + ((u0 >> 16) & 1u)) >> 16;   // RNE to bf16
    u1 = (u1 + 0x7fffu + ((u1 >> 16) & 1u)) >> 16;
    return u0 | (u1 << 16);
}

// ---------------- per-b-group barrier ---------------------------------------
__device__ __forceinline__ void groupbar(int bg, unsigned lgen, unsigned grp) {
    __syncthreads();
    if (threadIdx.x == 0) {
        unsigned* cnt = &g_bar_cnt[bg * 32];
        unsigned* gen = &g_bar_gen[bg * 32];
        unsigned prev = __hip_atomic_fetch_add(cnt, 1u, __ATOMIC_RELAXED,
                                               __HIP_MEMORY_SCOPE_AGENT);
        if (prev == lgen * grp - 1u) {
            __hip_atomic_store(gen, lgen, __ATOMIC_RELAXED,
                               __HIP_MEMORY_SCOPE_AGENT);
        } else {
            while (__hip_atomic_load(gen, __ATOMIC_RELAXED,
                                     __HIP_MEMORY_SCOPE_AGENT) < lgen)
                __builtin_amdgcn_s_sleep(1);
        }
    }
    __syncthreads();
}

// ---------------- init ------------------------------------------------------
__global__ void k_init(const float* __restrict__ h0,
                       const float* __restrict__ gW1, const float* __restrict__ gb1,
                       const float* __restrict__ gW2, const float* __restrict__ gb2,
                       const float* __restrict__ gWF, const float* __restrict__ gbF) {
    int blk = blockIdx.x, tid = threadIdx.x;
    if (blk < 256) {
        int idx = blk * 256 + tid;
        float v = h0[idx & (Hsz - 1)];
        g_h[0][0][idx] = v;
        g_h[1][0][idx] = v;
    } else if (blk == 256) {
        __shared__ float red[256];
        float s = 0.f;
        for (int j = tid; j < Hsz; j += 256) s += gWF[j] * (gb1[j] + gb2[j]);
        red[tid] = s;
        __syncthreads();
        for (int off = 128; off > 0; off >>= 1) {
            if (tid < off) red[tid] += red[tid + off];
            __syncthreads();
        }
        if (tid == 0) g_c = red[0] + gbF[0];
        if (tid < 128) ((float*)g_pre)[tid] = 0.f;
        if (tid >= 128 && tid < 256) {
            g_bar_cnt[tid - 128] = 0u;
            g_bar_gen[tid - 128] = 0u;
        }
    } else if (blk < 261) {
        int k = (blk - 257) * 256 + tid;
        float s = 0.f;
        for (int j = 0; j < Hsz; ++j) s += gWF[j] * gW1[(size_t)j * Hsz + k];
        g_v1[k] = s;
    } else {
        int k = (blk - 261) * 256 + tid;
        float s = 0.f;
        for (int j = 0; j < Hsz; ++j) s += gWF[j] * gW2[(size_t)j * Hsz + k];
        g_v2[k] = s;
    }
}

// ---------------- pack L0-Whh to bf16 pairs in global -----------------------
__global__ __launch_bounds__(256) void k_pack0(const float* __restrict__ W_hh) {
    const int r = blockIdx.x;            // 0..3071
    const float* src = W_hh + (size_t)r * Hsz;
    unsigned* dst = g_w0 + (size_t)r * WROWU;
    for (int i = threadIdx.x; i < WROWU; i += 256)
        dst[i] = rne_bf16_pair(src[2 * i], src[2 * i + 1]);
}

// ---------------- precompute an[t][b] = x[b, min(t+1,T-1)] . v1 -------------
__global__ void k_an(const float* __restrict__ x) {
    int blk = blockIdx.x, tid = threadIdx.x;
    int lane = tid & 63, wv = tid >> 6;
    for (int i = 0; i < 16; ++i) {
        int o = blk * 64 + wv * 16 + i;      // [0, 16384)
        int b = o >> 8, tt = o & 255;
        int ts = (tt + 1 < Tsz) ? tt + 1 : Tsz - 1;
        const float* xp = x + ((size_t)b * Tsz + ts) * Hsz;
        float s = 0.f;
        for (int k = lane; k < Hsz; k += 64) s += xp[k] * g_v1[k];
        for (int m = 32; m > 0; m >>= 1) s += __shfl_xor(s, m, 64);
        if (lane == 0) g_an[tt * 64 + b] = s;
    }
}

// ---------------- gi0 GEMM: g_gi0[t*64+b][n] = x[b,t,:].Wih0[n,:] + bih0[n] -
__global__ __launch_bounds__(256) void k_gemm(const float* __restrict__ x,
                                              const float* __restrict__ Wih,
                                              const float* __restrict__ bih) {
    __shared__ float As[16][132];
    __shared__ float Bs[16][132];
    const int tid = threadIdx.x;
    const int n0 = blockIdx.x * 128;   // 24 tiles
    const int m0 = blockIdx.y * 128;   // 128 tiles (C-row space r = t*64+b)
    const int tx = tid & 15, ty = tid >> 4;
    float acc[8][8] = {};

    for (int k0 = 0; k0 < Hsz; k0 += 16) {
#pragma unroll
        for (int i = 0; i < 2; ++i) {
            int task = tid * 2 + i;          // 0..511
            int rl = task >> 2;              // 0..127
            int kq = task & 3;
            int r = m0 + rl;
            int bb = r & 63, tt = r >> 6;
            float4 v = *(const float4*)(x + ((size_t)bb * Tsz + tt) * Hsz + k0 + kq * 4);
            As[kq * 4 + 0][rl] = v.x; As[kq * 4 + 1][rl] = v.y;
            As[kq * 4 + 2][rl] = v.z; As[kq * 4 + 3][rl] = v.w;
            float4 w = *(const float4*)(Wih + (size_t)(n0 + rl) * Hsz + k0 + kq * 4);
            Bs[kq * 4 + 0][rl] = w.x; Bs[kq * 4 + 1][rl] = w.y;
            Bs[kq * 4 + 2][rl] = w.z; Bs[kq * 4 + 3][rl] = w.w;
        }
        __syncthreads();
#pragma unroll
        for (int k = 0; k < 16; ++k) {
            float a[8], b[8];
            *(float4*)&a[0] = *(float4*)&As[k][ty * 8];
            *(float4*)&a[4] = *(float4*)&As[k][ty * 8 + 4];
            *(float4*)&b[0] = *(float4*)&Bs[k][tx * 8];
            *(float4*)&b[4] = *(float4*)&Bs[k][tx * 8 + 4];
#pragma unroll
            for (int i2 = 0; i2 < 8; ++i2)
#pragma unroll
                for (int j2 = 0; j2 < 8; ++j2) acc[i2][j2] += a[i2] * b[j2];
        }
        __syncthreads();
    }
#pragma unroll
    for (int i2 = 0; i2 < 8; ++i2) {
        int r = m0 + ty * 8 + i2;
        float* cp = g_gi0 + (size_t)r * (3 * Hsz) + n0 + tx * 8;
#pragma unroll
        for (int j2 = 0; j2 < 8; j2 += 4) {
            float4 v;
            v.x = acc[i2][j2 + 0] + bih[n0 + tx * 8 + j2 + 0];
            v.y = acc[i2][j2 + 1] + bih[n0 + tx * 8 + j2 + 1];
            v.z = acc[i2][j2 + 2] + bih[n0 + tx * 8 + j2 + 2];
            v.w = acc[i2][j2 + 3] + bih[n0 + tx * 8 + j2 + 3];
            *(float4*)(cp + j2) = v;
        }
    }
}

__device__ __forceinline__ float dot4(float4 a, float4 b) {
    return a.x * b.x + a.y * b.y + a.z * b.z + a.w * b.w;
}

// ---------------- phase A: L0-h (global bf16) + L1-h (global fp32) ----------
// WG tile 16b x 8jn; lane = (bi2: 8 b-pairs) x (ji: 8 jn). Wave K-window 128.
__device__ __forceinline__ void phaseA(
    int t, int b0, int jn0,
    const float* __restrict__ st0, float* __restrict__ ho0,
    const float* __restrict__ st1,
    const float* __restrict__ Whh1, const float* __restrict__ bh0,
    const float* __restrict__ h0,
    float (*s_act)[2][16][36], float (*s_red)[4][16][8],
    const float* __restrict__ s_rst,
    float (&axh)[3][2]) {

    const int tid = threadIdx.x;
    const int wv = tid >> 6, lane = tid & 63;
    const int bi2 = (lane & 7) * 2, ji = lane >> 3;
    const int kq0 = wv * 128;

    const unsigned* w0p[3];
    const float* w1p[3];
#pragma unroll
    for (int g = 0; g < 3; ++g) {
        int row = g * Hsz + jn0 + ji;
        w0p[g] = g_w0 + (size_t)row * WROWU;
        w1p[g] = Whh1 + (size_t)row * Hsz;
    }

    float acc0[3][2] = {};
#pragma unroll
    for (int m = 0; m < 3; ++m)
#pragma unroll
        for (int d = 0; d < 2; ++d) axh[m][d] = 0.f;

    auto issue_chunk = [&](int c, float4* dst) {
        const int kb = kq0 + c * 32;
#pragma unroll
        for (int i = 0; i < 4; ++i) {
            int o = (i & 1) * 64 + lane;
            int layer = i >> 1;
            int bb = (o >> 3) & 15, k4 = o & 7;
            int k = kb + k4 * 4;
            const float* p = (layer ? st1 : st0) + (size_t)(b0 + bb) * Hsz + k;
            ldc4_issue(p, dst[i]);
        }
    };
    auto patch_write = [&](int c, float4* src) {
        const int kb = kq0 + c * 32;
#pragma unroll
        for (int i = 0; i < 4; ++i) {
            int o = (i & 1) * 64 + lane;
            int layer = i >> 1;
            int bb = (o >> 3) & 15, k4 = o & 7;
            int k = kb + k4 * 4;
            float4 v = src[i];
            float4 hv = *(const float4*)(h0 + k);
            if (s_rst[bb] != 0.f) v = hv;
            *(float4*)&s_act[wv][layer][bb][k4 * 4] = v;
        }
    };
    auto compute_chunk = [&](int c) {
        const int kb = kq0 + c * 32;
#pragma unroll 2
        for (int kk = 0; kk < 32; kk += 4) {
            const int k = kb + kk;
            const int kw = k >> 1;
            float4 hA = *(const float4*)&s_act[wv][0][bi2][kk];
            float4 hB = *(const float4*)&s_act[wv][0][bi2 + 1][kk];
            float4 gA = *(const float4*)&s_act[wv][1][bi2][kk];
            float4 gB = *(const float4*)&s_act[wv][1][bi2 + 1][kk];
            // L0: global bf16 weights (L2-resident, 6 MB set)
            float4 whr = bfx4(*(const uint2*)(w0p[0] + kw));
            float4 whz = bfx4(*(const uint2*)(w0p[1] + kw));
            float4 whn = bfx4(*(const uint2*)(w0p[2] + kw));
            acc0[0][0] += dot4(hA, whr);
            acc0[0][1] += dot4(hB, whr);
            acc0[1][0] += dot4(hA, whz);
            acc0[1][1] += dot4(hB, whz);
            acc0[2][0] += dot4(hA, whn);
            acc0[2][1] += dot4(hB, whn);
            // L1-h: fp32 weights (overlapping stream)
            float4 w1r = *(const float4*)(w1p[0] + k);
            float4 w1z = *(const float4*)(w1p[1] + k);
            float4 w1n = *(const float4*)(w1p[2] + k);
            axh[0][0] += dot4(gA, w1r);
            axh[0][1] += dot4(gB, w1r);
            axh[1][0] += dot4(gA, w1z);
            axh[1][1] += dot4(gB, w1z);
            axh[2][0] += dot4(gA, w1n);
            axh[2][1] += dot4(gB, w1n);
        }
    };

    float4 C0[4], C1[4], C2[4], C3[4];
    issue_chunk(0, C0); issue_chunk(1, C1);
    issue_chunk(2, C2); issue_chunk(3, C3);
    WAITVM(12);
    patch_write(0, C0); compute_chunk(0);
    WAITVM(8);
    patch_write(1, C1); compute_chunk(1);
    WAITVM(4);
    patch_write(2, C2); compute_chunk(2);
    WAITVM(0);
    patch_write(3, C3); compute_chunk(3);

    __syncthreads();
    if (wv >= 4) {
#pragma unroll
        for (int m = 0; m < 3; ++m)
#pragma unroll
            for (int db = 0; db < 2; ++db)
                s_red[wv - 4][m][bi2 + db][ji] = acc0[m][db];
    }
    __syncthreads();
    if (wv < 4) {
#pragma unroll
        for (int m = 0; m < 3; ++m)
#pragma unroll
            for (int db = 0; db < 2; ++db)
                s_red[wv][m][bi2 + db][ji] += acc0[m][db];
    }
    __syncthreads();

    if (tid < 128) {
        const int ji2 = tid & 7, bI = tid >> 3;
        const int b = b0 + bI, jn = jn0 + ji2;
        float hprev = ldc(st0 + (size_t)b * Hsz + jn);
        const float* gp = g_gi0 + (size_t)(t * 64 + b) * (3 * Hsz) + jn;
        float g0r = gp[0];
        float g0z = gp[Hsz];
        float g0n = gp[2 * Hsz];
        float s[3];
#pragma unroll
        for (int m = 0; m < 3; ++m)
            s[m] = s_red[0][m][bI][ji2] + s_red[1][m][bI][ji2] +
                   s_red[2][m][bI][ji2] + s_red[3][m][bI][ji2];
        if (s_rst[bI] != 0.f) hprev = h0[jn];

        const float pr  = g0r + s[0] + bh0[jn];
        const float pz  = g0z + s[1] + bh0[Hsz + jn];
        const float pin = g0n;
        const float phn = s[2] + bh0[2 * Hsz + jn];
        const float r_ = 1.f / (1.f + __expf(-pr));
        const float z_ = 1.f / (1.f + __expf(-pz));
        const float n_ = tanhf(pin + r_ * phn);
        const float hnew = (1.f - z_) * n_ + z_ * hprev;
        stc(ho0 + (size_t)b * Hsz + jn, hnew);
    }
}

// ---------------- phase B: L1 x-matmul + epilogue (merges axh) --------------
__device__ __forceinline__ void phaseB(
    int t, int b0, int jn0,
    const float* __restrict__ a0,
    const float* __restrict__ st, float* __restrict__ ho,
    const float* __restrict__ Wih1,
    const float* __restrict__ bi, const float* __restrict__ bh,
    const float* __restrict__ h0, const int* __restrict__ lens,
    float* __restrict__ outp,
    float (*s_act)[2][16][36], float (*s_red)[4][16][8],
    const float* __restrict__ s_rst, float (*s_gs)[8],
    const float (&axh)[3][2]) {

    const int tid = threadIdx.x;
    const int wv = tid >> 6, lane = tid & 63;
    const int bi2 = (lane & 7) * 2, ji = lane >> 3;
    const int kq0 = wv * 128;

    const float* wpi[3];
#pragma unroll
    for (int g = 0; g < 3; ++g)
        wpi[g] = Wih1 + (size_t)(g * Hsz + jn0 + ji) * Hsz;

    float acc[3][2] = {};

    auto issue_chunk = [&](int c, float4* dst) {
        const int kb = kq0 + c * 32;
#pragma unroll
        for (int i = 0; i < 2; ++i) {
            int o = i * 64 + lane;
            int bb = (o >> 3) & 15, k4 = o & 7;
            int k = kb + k4 * 4;
            ldc4_issue(a0 + (size_t)(b0 + bb) * Hsz + k, dst[i]);
        }
    };
    auto write_chunk = [&](int c, float4* src) {
#pragma unroll
        for (int i = 0; i < 2; ++i) {
            int o = i * 64 + lane;
            int bb = (o >> 3) & 15, k4 = o & 7;
            *(float4*)&s_act[wv][0][bb][k4 * 4] = src[i];   // no reset patch
        }
    };
    auto compute_chunk = [&](int c) {
        const int kb = kq0 + c * 32;
#pragma unroll 2
        for (int kk = 0; kk < 32; kk += 4) {
            const int k = kb + kk;
            float4 xA = *(const float4*)&s_act[wv][0][bi2][kk];
            float4 xB = *(const float4*)&s_act[wv][0][bi2 + 1][kk];
            float4 wir = *(const float4*)(wpi[0] + k);
            float4 wiz = *(const float4*)(wpi[1] + k);
            float4 win = *(const float4*)(wpi[2] + k);
            acc[0][0] += dot4(xA, wir);
            acc[0][1] += dot4(xB, wir);
            acc[1][0] += dot4(xA, wiz);
            acc[1][1] += dot4(xB, wiz);
            acc[2][0] += dot4(xA, win);
            acc[2][1] += dot4(xB, win);
        }
    };

    float4 C0[2], C1[2], C2[2], C3[2];
    issue_chunk(0, C0); issue_chunk(1, C1);
    issue_chunk(2, C2); issue_chunk(3, C3);
    WAITVM(6);
    write_chunk(0, C0); compute_chunk(0);
    WAITVM(4);
    write_chunk(1, C1); compute_chunk(1);
    WAITVM(2);
    write_chunk(2, C2); compute_chunk(2);
    WAITVM(0);
    write_chunk(3, C3); compute_chunk(3);

    float m4[4][2];
#pragma unroll
    for (int db = 0; db < 2; ++db) {
        m4[0][db] = acc[0][db] + axh[0][db];
        m4[1][db] = acc[1][db] + axh[1][db];
        m4[2][db] = acc[2][db];
        m4[3][db] = axh[2][db];
    }

    __syncthreads();
    if (wv >= 4) {
#pragma unroll
        for (int m = 0; m < 4; ++m)
#pragma unroll
            for (int db = 0; db < 2; ++db)
                s_red[wv - 4][m][bi2 + db][ji] = m4[m][db];
    }
    __syncthreads();
    if (wv < 4) {
#pragma unroll
        for (int m = 0; m < 4; ++m)
#pragma unroll
            for (int db = 0; db < 2; ++db)
                s_red[wv][m][bi2 + db][ji] += m4[m][db];
    }
    __syncthreads();

    if (tid < 128) {
        const int ji2 = tid & 7, bI = tid >> 3;
        const int b = b0 + bI, jn = jn0 + ji2;
        float hprev = ldc(st + (size_t)b * Hsz + jn);
        const int lb = lens[b];
        float s[4];
#pragma unroll
        for (int m = 0; m < 4; ++m)
            s[m] = s_red[0][m][bI][ji2] + s_red[1][m][bI][ji2] +
                   s_red[2][m][bI][ji2] + s_red[3][m][bI][ji2];
        if (s_rst[bI] != 0.f) hprev = h0[jn];

        const float pr  = s[0] + bi[jn] + bh[jn];
        const float pz  = s[1] + bi[Hsz + jn] + bh[Hsz + jn];
        const float pin = s[2] + bi[2 * Hsz + jn];
        const float phn = s[3] + bh[2 * Hsz + jn];
        const float r_ = 1.f / (1.f + __expf(-pr));
        const float z_ = 1.f / (1.f + __expf(-pz));
        const float n_ = tanhf(pin + r_ * phn);
        const float hnew = (1.f - z_) * n_ + z_ * hprev;
        stc(ho + (size_t)b * Hsz + jn, hnew);
        outp[((size_t)b * Tsz + t) * Hsz + jn] = (t < lb) ? hnew : 0.f;
        s_gs[bI][ji2] = hnew * g_v2[jn];
    }
    __syncthreads();
    if (tid < 16) {
        float sm = 0.f;
#pragma unroll
        for (int j = 0; j < 8; ++j) sm += s_gs[tid][j];
        atomicAdd(&g_pre[t & 1][b0 + tid], sm);
    }
}

// ---------------- main persistent cooperative kernel ------------------------
// JC=1: grid 512 (4bg x 128jg of 8 cols), 2 WGs/CU (LDS 45.6 KB), 4 waves/SIMD.
// JC=2: grid 256 fallback, each WG runs 2 j-tiles (if occupancy query says 1).
template <int JC>
__global__ void __launch_bounds__(NTHR, 1)
k_main(const float* __restrict__ h0, const int* __restrict__ lens,
       const float* __restrict__ W_ih, const float* __restrict__ W_hh,
       const float* __restrict__ b_ih, const float* __restrict__ b_hh,
       float* __restrict__ outp, float* __restrict__ gatep) {
    __shared__ __align__(16) float s_act[8][2][16][36];  // 36.9 KB
    __shared__ float s_red[4][4][16][8];                 // 8.2 KB
    __shared__ float s_rst[16];
    __shared__ float s_gs[16][8];

    constexpr int JSHIFT = (JC == 1) ? 7 : 6;
    constexpr unsigned GRP = (JC == 1) ? 128u : 64u;

    const int tid = threadIdx.x;
    const int wg = blockIdx.x;
    const int bg = wg >> JSHIFT, jbase = wg & (GRP - 1);
    const int b0 = bg * 16;
    unsigned lgen = 0;

    const float* Wih1 = W_ih + (size_t)3 * Hsz * Hsz;
    const float* Whh1 = W_hh + (size_t)3 * Hsz * Hsz;
    const float* bi1 = b_ih + 3 * Hsz;
    const float* bh1 = b_hh + 3 * Hsz;

    float axh[JC][3][2];

    for (int t = 0; t < Tsz; ++t) {
        const int p0 = t & 1, p1 = p0 ^ 1;

        // prologue: reset flags from previous step's gate; emit gate_z
        if (tid < 16) {
            float rstf = 0.f;
            const int b = b0 + tid;
            const int lb = lens[b];
            if (t > 0) {
                const int tp = t - 1;
                const float pre = g_c + g_an[tp * 64 + b] + ldc(&g_pre[p1][b]);
                const bool il = (tp == lb - 1);
                rstf = (il || pre > 0.f) ? 1.f : 0.f;
                if (jbase == 0) {
                    const float gt = il ? 1.f : 1.f / (1.f + __expf(-pre));
                    gatep[(size_t)b * Tsz + tp] = (tp < lb) ? gt : 0.f;
                }
            }
            s_rst[tid] = rstf;
        }
        __syncthreads();

        // phase A: L0 (gi from g_gi0, h from global bf16) + L1-h (fp32)
#pragma unroll
        for (int j = 0; j < JC; ++j)
            phaseA(t, b0, (jbase + j * (int)GRP) * 8,
                   g_h[0][p0], g_h[0][p1], g_h[1][p0],
                   Whh1, b_hh, h0, s_act, s_red, s_rst, axh[j]);
        groupbar(bg, ++lgen, GRP);

        // zero next step's gate accumulator (parity p1, already consumed)
        if (jbase == 0 && tid < 16) stc(&g_pre[p1][b0 + tid], 0.f);

        // phase B: L1-x from fresh h_L0(t) + merged epilogue
#pragma unroll
        for (int j = 0; j < JC; ++j)
            phaseB(t, b0, (jbase + j * (int)GRP) * 8,
                   g_h[0][p1], g_h[1][p0], g_h[1][p1],
                   Wih1, bi1, bh1, h0, lens,
                   outp, s_act, s_red, s_rst, s_gs, axh[j]);
        groupbar(bg, ++lgen, GRP);
    }

    // tail: gate_z for tp = T-1
    if (jbase == 0 && tid < 16) {
        const int b = b0 + tid;
        const int lb = lens[b];
        const int tp = Tsz - 1;
        const float pre = g_c + g_an[tp * 64 + b] + ldc(&g_pre[tp & 1][b]);
        const bool il = (tp == lb - 1);
        const float gt = il ? 1.f : 1.f / (1.f + __expf(-pre));
        gatep[(size_t)b * Tsz + tp] = (tp < lb) ? gt : 0.f;
    }
}

// ---------------- host launcher ---------------------------------------------
extern "C" void kernel_launch(void* const* d_in, const int* in_sizes, int n_in,
                              void* d_out, int out_size, void* d_ws, size_t ws_size,
                              hipStream_t stream) {
    const float* x = (const float*)d_in[0];
    const float* h0 = (const float*)d_in[1];
    const int* lens = (const int*)d_in[2];
    const float* W_ih = (const float*)d_in[3];
    const float* W_hh = (const float*)d_in[4];
    const float* b_ih = (const float*)d_in[5];
    const float* b_hh = (const float*)d_in[6];
    const float* gW1 = (const float*)d_in[7];
    const float* gb1 = (const float*)d_in[8];
    const float* gW2 = (const float*)d_in[9];
    const float* gb2 = (const float*)d_in[10];
    const float* gWF = (const float*)d_in[11];
    const float* gbF = (const float*)d_in[12];
    float* outp = (float*)d_out;
    float* gatep = outp + (size_t)Bsz * Tsz * Hsz;

    hipLaunchKernelGGL(k_init, dim3(265), dim3(256), 0, stream,
                       h0, gW1, gb1, gW2, gb2, gWF, gbF);
    hipLaunchKernelGGL(k_pack0, dim3(3072), dim3(256), 0, stream, W_hh);
    hipLaunchKernelGGL(k_an, dim3(256), dim3(256), 0, stream, x);
    hipLaunchKernelGGL(k_gemm, dim3(24, 128), dim3(256), 0, stream,
                       x, W_ih, b_ih);

    // pure host-side occupancy query (graph-capture-safe), cached
    static int s_mode = 0;
    if (s_mode == 0) {
        int mb = 0;
        if (hipOccupancyMaxActiveBlocksPerMultiprocessor(
                &mb, (const void*)k_main<1>, NTHR, 0) != hipSuccess) mb = 1;
        s_mode = (mb >= 2) ? 1 : 2;
    }

    void* args[8] = { (void*)&h0, (void*)&lens, (void*)&W_ih, (void*)&W_hh,
                      (void*)&b_ih, (void*)&b_hh, (void*)&outp, (void*)&gatep };
    hipError_t err;
    if (s_mode == 1) {
        err = hipLaunchCooperativeKernel((const void*)k_main<1>, dim3(512),
                                         dim3(NTHR), args, 0, stream);
    } else {
        err = hipLaunchCooperativeKernel((const void*)k_main<2>, dim3(256),
                                         dim3(NTHR), args, 0, stream);
    }
    (void)err;
}